// Round 12
// baseline (534.155 us; speedup 1.0000x reference)
//
#include <hip/hip_runtime.h>
#include <hip/hip_bf16.h>

#define N_USER 50000
#define N_ITEM 30000
#define NTOT   80000
#define EMB    64
#define FAC    4
#define EDGES  1000000
#define LOG4   1.3862943611198906f
#define SB     1024
#define NBLK   79   // ceil(80000/1024)
#define KP     16   // scatter h-partitions
#define PB     256  // blocks per partition
#define CHUNK  3907 // ceil(EDGES/PB)

// ws layout (float idx), ~80 MB:
//   P     +0          4,000,000  (softmax probs of A, CSR position order)
//   dv0   +4,000,000    320,000  (dvinv / raw-dval ping)
//   dv1   +4,320,000    320,000  (dvinv / raw-dval pong)
//   rhn   +4,640,000    320,000
//   bufW  +4,960,000  2,560,000  (bf16: input ego; later p3 output f3)
//   bufX  +7,520,000  2,560,000  (bf16: f0 / f2)
//   bufY  +10,080,000 2,560,000  (bf16: f1 = layer-1 input, kept for k_final)
//   bufZ0 +12,640,000 2,560,000  (bf16: layer-0 tanh-norm)
//   bufZ1 +15,200,000 2,560,000  (bf16: layer-1 tanh-norm)
//   flag  +17,760,000 16
//   deg   +17,760,016 80,000 | off +17,840,016 80,001 | cur +17,920,017 80,000
//   tlist +18,000,017 1,000,000 | hlist +19,000,017 1,000,000
//   bsum  +20,000,017 128 | bbase +20,000,145 128

__device__ inline float bf2f(unsigned short u) {
    return __uint_as_float(((unsigned int)u) << 16);
}
__device__ inline unsigned short f2bf(float f) {
    unsigned int x = __float_as_uint(f);
    x += 0x7FFFu + ((x >> 16) & 1u);       // round-to-nearest-even
    return (unsigned short)(x >> 16);
}
__device__ inline float dot2(unsigned int a, unsigned int b) {
    float a0 = __uint_as_float(a << 16), a1 = __uint_as_float(a & 0xFFFF0000u);
    float b0 = __uint_as_float(b << 16), b1 = __uint_as_float(b & 0xFFFF0000u);
    return a0 * b0 + a1 * b1;
}

// ---- input dtype detector (fp32 read-as-bf16 shows inf/NaN bit patterns) ----
__global__ void k_detect(const unsigned short* __restrict__ raw, int* __restrict__ flag) {
    __shared__ int s;
    if (threadIdx.x == 0) s = 0;
    __syncthreads();
    int c = 0;
    for (int i = threadIdx.x; i < 16384; i += 256) {
        unsigned short u = raw[i];
        if ((u & 0x7F80) == 0x7F80) c++;
    }
    atomicAdd(&s, c);
    __syncthreads();
    if (threadIdx.x == 0) *flag = (s > 0) ? 1 : 0;  // 1 => fp32
}

// ---- init: ego(bf16) + layer-0 tnh (no out write; k_final reads raw inputs) ----
__global__ void k_init(const void* __restrict__ ue, const void* __restrict__ ie,
                       const int* __restrict__ flag,
                       unsigned short* __restrict__ egoh,
                       unsigned short* __restrict__ tnh0) {
    int gid = blockIdx.x * blockDim.x + threadIdx.x;
    int wid = gid >> 6;
    int lane = threadIdx.x & 63;
    if (wid >= NTOT) return;
    int i = wid * 64 + lane;
    bool isf32 = (*flag != 0);
    float v;
    if (i < N_USER * EMB) {
        v = isf32 ? ((const float*)ue)[i]
                  : __bfloat162float(((const __hip_bfloat16*)ue)[i]);
    } else {
        int j = i - N_USER * EMB;
        v = isf32 ? ((const float*)ie)[j]
                  : __bfloat162float(((const __hip_bfloat16*)ie)[j]);
    }
    egoh[i] = f2bf(v);
    float ss = v * v;
    ss += __shfl_xor(ss, 1); ss += __shfl_xor(ss, 2);
    ss += __shfl_xor(ss, 4); ss += __shfl_xor(ss, 8);
    float rr = 1.0f / fmaxf(sqrtf(ss), 1e-12f);
    tnh0[i] = f2bf(tanhf(v * rr));
}

// ---- CSR build ----
__global__ void k_deg(const int* __restrict__ h, int* __restrict__ deg) {
    int e = blockIdx.x * blockDim.x + threadIdx.x;
    if (e < EDGES) atomicAdd(&deg[h[e]], 1);
}

__global__ void k_scan1(const int* __restrict__ deg, int* __restrict__ off,
                        int* __restrict__ bsum) {
    __shared__ int buf[SB];
    int tid = threadIdx.x;
    int i = blockIdx.x * SB + tid;
    int v = (i < NTOT) ? deg[i] : 0;
    buf[tid] = v;
    __syncthreads();
    for (int s = 1; s < SB; s <<= 1) {
        int t = (tid >= s) ? buf[tid - s] : 0;
        __syncthreads();
        buf[tid] += t;
        __syncthreads();
    }
    if (i < NTOT) off[i] = buf[tid] - v;
    if (tid == SB - 1) bsum[blockIdx.x] = buf[tid];
}

__global__ void k_scan2(const int* __restrict__ bsum, int* __restrict__ bbase) {
    __shared__ int b[128];
    int tid = threadIdx.x;
    int v = (tid < NBLK) ? bsum[tid] : 0;
    b[tid] = v;
    __syncthreads();
    for (int s = 1; s < 128; s <<= 1) {
        int t = (tid >= s) ? b[tid - s] : 0;
        __syncthreads();
        b[tid] += t;
        __syncthreads();
    }
    if (tid < NBLK) bbase[tid] = b[tid] - v;
}

// fused: also emit pass-0 dvinv = rsqrt(0.25*deg)  (softmax of all-ones logits)
__global__ void k_scan3(int* __restrict__ off, const int* __restrict__ bbase,
                        int* __restrict__ cur, const int* __restrict__ deg,
                        float* __restrict__ dv0) {
    int i = blockIdx.x * blockDim.x + threadIdx.x;
    if (i < NTOT) {
        int o = off[i] + bbase[i >> 10];
        off[i] = o;
        cur[i] = o;
        float d = rsqrtf(fmaxf(0.25f * (float)deg[i], 1e-8f));
        ((float4*)dv0)[i] = make_float4(d, d, d, d);
    }
    if (i == 0) off[NTOT] = EDGES;
}

// ---- h-partitioned multisplit scatter: partition k writes only h in
// [k*5000,(k+1)*5000) so its 1 MB output slice stays L2-resident while
// filling (kills the 8x write churn of the single-pass version).
// Partition-major grid => partitions run roughly sequentially.
__global__ void k_scatter(const int* __restrict__ hl, const int* __restrict__ tl,
                          int* __restrict__ cur,
                          int* __restrict__ tlist, int* __restrict__ hlist) {
    int part = blockIdx.x / PB;
    int blk  = blockIdx.x % PB;
    int lo = part * (NTOT / KP), hi = lo + (NTOT / KP);
    int base = blk * CHUNK;
    int end = base + CHUNK; if (end > EDGES) end = EDGES;
    for (int e = base + (int)threadIdx.x; e < end; e += 256) {
        int hh = hl[e];
        if (hh >= lo && hh < hi) {
            int pos = atomicAdd(&cur[hh], 1);
            tlist[pos] = tl[e];
            hlist[pos] = hh;
        }
    }
}

// ---- a: raw dval -> dvinv in place; z: zero for the next accumulation ----
__global__ void k_rsq(float* __restrict__ a, float* __restrict__ z) {
    int i = blockIdx.x * blockDim.x + threadIdx.x;
    if (i >= NTOT * FAC) return;
    a[i] = rsqrtf(fmaxf(a[i], 1e-8f));
    z[i] = 0.f;
}

// ---- message passing, gather form; weight = P * dvinv_h * dvinv_t ----
__global__ void k_mp(const unsigned short* __restrict__ egoh, const float* __restrict__ P,
                     const float* __restrict__ dvinv, const int* __restrict__ off,
                     const int* __restrict__ tlist,
                     unsigned short* __restrict__ fach, float* __restrict__ rhn,
                     unsigned short* __restrict__ tnhOut,
                     int useP, int writeRhn, int writeTnh) {
    int gid = blockIdx.x * blockDim.x + threadIdx.x;
    int wid = gid >> 6;
    int lane = threadIdx.x & 63;
    if (wid >= NTOT) return;
    int f = lane >> 4;
    int beg = off[wid], end = off[wid + 1];
    float dvh = dvinv[wid * 4 + f];
    float acc = 0.f;
    int j = beg;
    for (; j + 4 <= end; j += 4) {
        int t0 = tlist[j], t1 = tlist[j + 1], t2 = tlist[j + 2], t3 = tlist[j + 3];
        float w0, w1, w2, w3;
        if (useP) {
            w0 = P[(j + 0) * 4 + f]; w1 = P[(j + 1) * 4 + f];
            w2 = P[(j + 2) * 4 + f]; w3 = P[(j + 3) * 4 + f];
        } else {
            w0 = w1 = w2 = w3 = 0.25f;
        }
        float d0 = dvinv[t0 * 4 + f], d1 = dvinv[t1 * 4 + f],
              d2 = dvinv[t2 * 4 + f], d3 = dvinv[t3 * 4 + f];
        float g0 = bf2f(egoh[(size_t)t0 * 64 + lane]),
              g1 = bf2f(egoh[(size_t)t1 * 64 + lane]),
              g2 = bf2f(egoh[(size_t)t2 * 64 + lane]),
              g3 = bf2f(egoh[(size_t)t3 * 64 + lane]);
        acc += w0 * d0 * g0 + w1 * d1 * g1 + w2 * d2 * g2 + w3 * d3 * g3;
    }
    for (; j < end; ++j) {
        int t = tlist[j];
        float w = useP ? P[j * 4 + f] : 0.25f;
        acc += w * dvinv[t * 4 + f] * bf2f(egoh[(size_t)t * 64 + lane]);
    }
    acc *= dvh;
    fach[wid * 64 + lane] = f2bf(acc);
    if (writeRhn || writeTnh) {
        float ss = acc * acc;
        ss += __shfl_xor(ss, 1); ss += __shfl_xor(ss, 2);
        ss += __shfl_xor(ss, 4); ss += __shfl_xor(ss, 8);
        float rr = 1.0f / fmaxf(sqrtf(ss), 1e-12f);
        if (writeRhn && (lane & 15) == 0) rhn[wid * 4 + f] = rr;
        if (writeTnh) tnhOut[wid * 64 + lane] = f2bf(tanhf(acc * rr));
    }
}

// ---- routing update + fused dval via CSR-contiguous segmented reduction ----
__global__ void k_upd(const unsigned short* __restrict__ fach,
                      const unsigned short* __restrict__ tnhh,
                      const float* __restrict__ rhn,
                      const int* __restrict__ hlist, const int* __restrict__ tlist,
                      float* __restrict__ P, float* __restrict__ dval, int first) {
    __shared__ int   s_h[256];
    __shared__ float s_p[256][4];
    int tid = threadIdx.x;
    int j = blockIdx.x * 256 + tid;
    int h = -1;
    if (j < EDGES) {
        h = hlist[j];
        int t = tlist[j];
        const uint4* frow = (const uint4*)(fach + (size_t)h * 64);
        const uint4* trow = (const uint4*)(tnhh + (size_t)t * 64);
        float d[4];
#pragma unroll
        for (int f = 0; f < 4; ++f) {
            uint4 a0 = frow[f * 2], a1 = frow[f * 2 + 1];
            uint4 b0 = trow[f * 2], b1 = trow[f * 2 + 1];
            d[f] = dot2(a0.x, b0.x) + dot2(a0.y, b0.y)
                 + dot2(a0.z, b0.z) + dot2(a0.w, b0.w)
                 + dot2(a1.x, b1.x) + dot2(a1.y, b1.y)
                 + dot2(a1.z, b1.z) + dot2(a1.w, b1.w);
        }
        float4 rh = ((const float4*)rhn)[h];
        float lx, ly, lz, lw;
        if (first) { lx = ly = lz = lw = -LOG4; }
        else {
            float4 p0 = ((const float4*)P)[j];
            lx = __logf(p0.x); ly = __logf(p0.y);
            lz = __logf(p0.z); lw = __logf(p0.w);
        }
        float y0 = lx + rh.x * d[0], y1 = ly + rh.y * d[1],
              y2 = lz + rh.z * d[2], y3 = lw + rh.w * d[3];
        float m = fmaxf(fmaxf(y0, y1), fmaxf(y2, y3));
        float e0 = __expf(y0 - m), e1 = __expf(y1 - m),
              e2 = __expf(y2 - m), e3 = __expf(y3 - m);
        float inv = 1.0f / (e0 + e1 + e2 + e3);
        float p0n = e0 * inv, p1n = e1 * inv, p2n = e2 * inv, p3n = e3 * inv;
        ((float4*)P)[j] = make_float4(p0n, p1n, p2n, p3n);
        s_p[tid][0] = p0n; s_p[tid][1] = p1n; s_p[tid][2] = p2n; s_p[tid][3] = p3n;
    }
    s_h[tid] = h;
    __syncthreads();
    if (h == -1) return;
    if (tid > 0 && s_h[tid - 1] == h) return;   // not a segment head
    float a0 = 0.f, a1 = 0.f, a2 = 0.f, a3 = 0.f;
    int k = tid;
    while (k < 256 && s_h[k] == h) {
        a0 += s_p[k][0]; a1 += s_p[k][1]; a2 += s_p[k][2]; a3 += s_p[k][3];
        ++k;
    }
    float* dst = dval + (size_t)h * 4;
    if (tid == 0 || k == 256) {   // may continue in adjacent block -> atomic
        unsafeAtomicAdd(dst + 0, a0);
        unsafeAtomicAdd(dst + 1, a1);
        unsafeAtomicAdd(dst + 2, a2);
        unsafeAtomicAdd(dst + 3, a3);
    } else {                      // fully interior segment -> plain store
        ((float4*)dst)[0] = make_float4(a0, a1, a2, a3);
    }
}

// ---- final: out = (input + f1 + f3) / 3, single streaming pass ----
__global__ void k_final(const void* __restrict__ ue, const void* __restrict__ ie,
                        const int* __restrict__ flag,
                        const unsigned short* __restrict__ f1,
                        const unsigned short* __restrict__ f3,
                        float* __restrict__ out) {
    int i = blockIdx.x * blockDim.x + threadIdx.x;
    if (i >= NTOT * EMB) return;
    bool isf32 = (*flag != 0);
    float v;
    if (i < N_USER * EMB) {
        v = isf32 ? ((const float*)ue)[i]
                  : __bfloat162float(((const __hip_bfloat16*)ue)[i]);
    } else {
        int j = i - N_USER * EMB;
        v = isf32 ? ((const float*)ie)[j]
                  : __bfloat162float(((const __hip_bfloat16*)ie)[j]);
    }
    out[i] = (v + bf2f(f1[i]) + bf2f(f3[i])) * (1.0f / 3.0f);
}

extern "C" void kernel_launch(void* const* d_in, const int* in_sizes, int n_in,
                              void* d_out, int out_size, void* d_ws, size_t ws_size,
                              hipStream_t stream) {
    const void* ue = d_in[0];
    const void* ie = d_in[1];
    const int* hl = (const int*)d_in[2];
    const int* tl = (const int*)d_in[3];
    float* out = (float*)d_out;

    float* ws   = (float*)d_ws;
    float* P    = ws;
    float* dv0  = ws + 4000000;
    float* dv1  = ws + 4320000;
    float* rhn  = ws + 4640000;
    unsigned short* bufW = (unsigned short*)(ws + 4960000);   // input ego; later f3
    unsigned short* bufX = (unsigned short*)(ws + 7520000);   // f0 / f2
    unsigned short* bufY = (unsigned short*)(ws + 10080000);  // f1 (layer-1 input)
    unsigned short* bufZ0 = (unsigned short*)(ws + 12640000); // layer-0 tnh
    unsigned short* bufZ1 = (unsigned short*)(ws + 15200000); // layer-1 tnh
    int*   flag = (int*)(ws + 17760000);
    int*   deg  = (int*)(ws + 17760016);
    int*   off  = (int*)(ws + 17840016);
    int*   cur  = (int*)(ws + 17920017);
    int*   tlist = (int*)(ws + 18000017);
    int*   hlist = (int*)(ws + 19000017);
    int*   bsum  = (int*)(ws + 20000017);
    int*   bbase = (int*)(ws + 20000145);

    k_detect<<<1, 256, 0, stream>>>((const unsigned short*)ue, flag);
    k_init<<<20000, 256, 0, stream>>>(ue, ie, flag, bufW, bufZ0);

    hipMemsetAsync(deg, 0, NTOT * sizeof(int), stream);
    k_deg<<<3907, 256, 0, stream>>>(hl, deg);
    k_scan1<<<NBLK, SB, 0, stream>>>(deg, off, bsum);
    k_scan2<<<1, 128, 0, stream>>>(bsum, bbase);
    k_scan3<<<313, 256, 0, stream>>>(off, bbase, cur, deg, dv0);
    k_scatter<<<KP * PB, 256, 0, stream>>>(hl, tl, cur, tlist, hlist);
    hipMemsetAsync(dv1, 0, NTOT * FAC * sizeof(float), stream);

    // layer 0
    k_mp<<<20000, 256, 0, stream>>>(bufW, P, dv0, off, tlist, bufX, rhn, bufZ1,
                                    0, 1, 0);                        // p0 -> f0=X
    k_upd<<<3907, 256, 0, stream>>>(bufX, bufZ0, rhn, hlist, tlist, P, dv1, 1);
    k_rsq<<<1250, 256, 0, stream>>>(dv1, dv0);
    k_mp<<<20000, 256, 0, stream>>>(bufW, P, dv1, off, tlist, bufY, rhn, bufZ1,
                                    1, 1, 1);                        // p1 -> f1=Y (+tnh1)
    k_upd<<<3907, 256, 0, stream>>>(bufY, bufZ0, rhn, hlist, tlist, P, dv0, 0);
    k_rsq<<<1250, 256, 0, stream>>>(dv0, dv1);
    // layer 1 (ego = Y)
    k_mp<<<20000, 256, 0, stream>>>(bufY, P, dv0, off, tlist, bufX, rhn, bufZ1,
                                    1, 1, 0);                        // p2 -> f2=X
    k_upd<<<3907, 256, 0, stream>>>(bufX, bufZ1, rhn, hlist, tlist, P, dv1, 0);
    k_rsq<<<1250, 256, 0, stream>>>(dv1, dv0);
    k_mp<<<20000, 256, 0, stream>>>(bufY, P, dv1, off, tlist, bufW, rhn, bufZ1,
                                    1, 0, 0);                        // p3 -> f3=W
    k_final<<<20000, 256, 0, stream>>>(ue, ie, flag, bufY, bufW, out);
}

// Round 13
// 522.587 us; speedup vs baseline: 1.0221x; 1.0221x over previous
//
#include <hip/hip_runtime.h>
#include <hip/hip_bf16.h>

#define N_USER 50000
#define N_ITEM 30000
#define NTOT   80000
#define EMB    64
#define FAC    4
#define EDGES  1000000
#define LOG4   1.3862943611198906f
#define SB     1024
#define NBLK   79    // ceil(80000/1024)
#define NBUCK  512   // h-buckets for CSR build
#define BBLK   512   // blocks in count/scatter phases
#define BCH    1954  // ceil(EDGES/BBLK)

// ws layout (float idx), ~90 MB:
//   P     +0          4,000,000  (softmax probs; ALSO overlapped early by bt/cnt/gbase:
//                                 bt +0 (1,000,000) | cnt +1,000,000 (262,144) |
//                                 gbase +1,262,144 (262,144) — all dead before P is first
//                                 written (k_upd p0); k_mp p0 has useP=0 and never reads P)
//   dvacc +4,000,000    320,000  (raw dval accumulator)
//   dvinv +4,320,000    320,000
//   rhn   +4,640,000    320,000
//   bufW  +4,960,000  2,560,000  (bf16: input ego; later f3)
//   bufX  +7,520,000  2,560,000  (bf16: f0 / f2)
//   bufY  +10,080,000 2,560,000  (bf16: f1 = layer-1 input)
//   bufZ0 +12,640,000 2,560,000  (bf16: layer-0 tanh-norm)
//   bufZ1 +15,200,000 2,560,000  (bf16: layer-1 tanh-norm)
//   egoS  +17,760,000 2,560,000  (bf16: ego*dvinv_t, rebuilt per pass)
//   flag  +20,320,000 16
//   deg   +20,320,016 80,000 | off +20,400,016 80,001
//   tlist +20,480,017 1,000,000 | hlist +21,480,017 1,000,000
//   bsum  +22,480,017 128 | bbase +22,480,145 128

__device__ inline float bf2f(unsigned short u) {
    return __uint_as_float(((unsigned int)u) << 16);
}
__device__ inline unsigned short f2bf(float f) {
    unsigned int x = __float_as_uint(f);
    x += 0x7FFFu + ((x >> 16) & 1u);       // round-to-nearest-even
    return (unsigned short)(x >> 16);
}
__device__ inline float dot2(unsigned int a, unsigned int b) {
    float a0 = __uint_as_float(a << 16), a1 = __uint_as_float(a & 0xFFFF0000u);
    float b0 = __uint_as_float(b << 16), b1 = __uint_as_float(b & 0xFFFF0000u);
    return a0 * b0 + a1 * b1;
}
__device__ inline int bucket_of(int h) { return (int)(((unsigned)h * NBUCK) / (unsigned)NTOT); }
__device__ inline int bucket_lo(int k) { return (k * NTOT + NBUCK - 1) / NBUCK; }

// ---- input dtype detector (fp32 read-as-bf16 shows inf/NaN bit patterns) ----
__global__ void k_detect(const unsigned short* __restrict__ raw, int* __restrict__ flag) {
    __shared__ int s;
    if (threadIdx.x == 0) s = 0;
    __syncthreads();
    int c = 0;
    for (int i = threadIdx.x; i < 16384; i += 256) {
        unsigned short u = raw[i];
        if ((u & 0x7F80) == 0x7F80) c++;
    }
    atomicAdd(&s, c);
    __syncthreads();
    if (threadIdx.x == 0) *flag = (s > 0) ? 1 : 0;  // 1 => fp32
}

// ---- init: ego(bf16) + layer-0 tnh ----
__global__ void k_init(const void* __restrict__ ue, const void* __restrict__ ie,
                       const int* __restrict__ flag,
                       unsigned short* __restrict__ egoh,
                       unsigned short* __restrict__ tnh0) {
    int gid = blockIdx.x * blockDim.x + threadIdx.x;
    int wid = gid >> 6;
    int lane = threadIdx.x & 63;
    if (wid >= NTOT) return;
    int i = wid * 64 + lane;
    bool isf32 = (*flag != 0);
    float v;
    if (i < N_USER * EMB) {
        v = isf32 ? ((const float*)ue)[i]
                  : __bfloat162float(((const __hip_bfloat16*)ue)[i]);
    } else {
        int j = i - N_USER * EMB;
        v = isf32 ? ((const float*)ie)[j]
                  : __bfloat162float(((const __hip_bfloat16*)ie)[j]);
    }
    egoh[i] = f2bf(v);
    float ss = v * v;
    ss += __shfl_xor(ss, 1); ss += __shfl_xor(ss, 2);
    ss += __shfl_xor(ss, 4); ss += __shfl_xor(ss, 8);
    float rr = 1.0f / fmaxf(sqrtf(ss), 1e-12f);
    tnh0[i] = f2bf(tanhf(v * rr));
}

// ---- node-degree CSR offsets ----
__global__ void k_deg(const int* __restrict__ h, int* __restrict__ deg) {
    int e = blockIdx.x * blockDim.x + threadIdx.x;
    if (e < EDGES) atomicAdd(&deg[h[e]], 1);
}

__global__ void k_scan1(const int* __restrict__ deg, int* __restrict__ off,
                        int* __restrict__ bsum) {
    __shared__ int buf[SB];
    int tid = threadIdx.x;
    int i = blockIdx.x * SB + tid;
    int v = (i < NTOT) ? deg[i] : 0;
    buf[tid] = v;
    __syncthreads();
    for (int s = 1; s < SB; s <<= 1) {
        int t = (tid >= s) ? buf[tid - s] : 0;
        __syncthreads();
        buf[tid] += t;
        __syncthreads();
    }
    if (i < NTOT) off[i] = buf[tid] - v;
    if (tid == SB - 1) bsum[blockIdx.x] = buf[tid];
}

__global__ void k_scan2(const int* __restrict__ bsum, int* __restrict__ bbase) {
    __shared__ int b[128];
    int tid = threadIdx.x;
    int v = (tid < NBLK) ? bsum[tid] : 0;
    b[tid] = v;
    __syncthreads();
    for (int s = 1; s < 128; s <<= 1) {
        int t = (tid >= s) ? b[tid - s] : 0;
        __syncthreads();
        b[tid] += t;
        __syncthreads();
    }
    if (tid < NBLK) bbase[tid] = b[tid] - v;
}

// fused: also emit pass-0 RAW dval = 0.25*deg into dvacc
__global__ void k_scan3(int* __restrict__ off, const int* __restrict__ bbase,
                        const int* __restrict__ deg, float* __restrict__ dvacc) {
    int i = blockIdx.x * blockDim.x + threadIdx.x;
    if (i < NTOT) {
        off[i] = off[i] + bbase[i >> 10];
        float d = 0.25f * (float)deg[i];
        ((float4*)dvacc)[i] = make_float4(d, d, d, d);
    }
    if (i == 0) off[NTOT] = EDGES;
}

// ---- CSR build via bucket sort (single-writer windows; round-12 lesson) ----
// phase A: per-block LDS histogram over 512 buckets
__global__ void k_bcnt(const int* __restrict__ hl, int* __restrict__ cnt) {
    __shared__ int hist[NBUCK];
    int b = blockIdx.x, tid = threadIdx.x;
    for (int i = tid; i < NBUCK; i += 256) hist[i] = 0;
    __syncthreads();
    int base = b * BCH, end = base + BCH; if (end > EDGES) end = EDGES;
    for (int e = base + tid; e < end; e += 256)
        atomicAdd(&hist[bucket_of(hl[e])], 1);
    __syncthreads();
    for (int i = tid; i < NBUCK; i += 256) cnt[b * NBUCK + i] = hist[i];
}

// phase B: per-bucket exclusive scan over blocks, + off[lo(k)]
__global__ void k_bscan(const int* __restrict__ cnt, const int* __restrict__ off,
                        int* __restrict__ gbase) {
    __shared__ int buf[BBLK];
    int k = blockIdx.x, tid = threadIdx.x;  // 512 threads, tid = block index b
    int v = cnt[tid * NBUCK + k];
    buf[tid] = v;
    __syncthreads();
    for (int s = 1; s < BBLK; s <<= 1) {
        int t = (tid >= s) ? buf[tid - s] : 0;
        __syncthreads();
        buf[tid] += t;
        __syncthreads();
    }
    gbase[tid * NBUCK + k] = off[bucket_lo(k)] + buf[tid] - v;
}

// phase C: bucketize edges; pack (h-lo)<<17 | t in 4B
__global__ void k_bscat(const int* __restrict__ hl, const int* __restrict__ tl,
                        const int* __restrict__ gbase, int* __restrict__ bt) {
    __shared__ int lg[NBUCK];
    int b = blockIdx.x, tid = threadIdx.x;
    for (int i = tid; i < NBUCK; i += 256) lg[i] = gbase[b * NBUCK + i];
    __syncthreads();
    int base = b * BCH, end = base + BCH; if (end > EDGES) end = EDGES;
    for (int e = base + tid; e < end; e += 256) {
        int h = hl[e];
        int k = bucket_of(h);
        int pos = atomicAdd(&lg[k], 1);
        bt[pos] = ((h - bucket_lo(k)) << 17) | tl[e];
    }
}

// phase D: one block per bucket -> final CSR order in the bucket's private window
__global__ void k_bfin(const int* __restrict__ bt, const int* __restrict__ off,
                       int* __restrict__ tlist, int* __restrict__ hlist) {
    __shared__ int lcur[160];
    int k = blockIdx.x, tid = threadIdx.x;
    int lo = bucket_lo(k), hi = bucket_lo(k + 1);
    int nn = hi - lo;
    for (int i = tid; i < nn; i += 256) lcur[i] = off[lo + i];
    __syncthreads();
    int start = off[lo], end = off[hi];
    for (int j = start + tid; j < end; j += 256) {
        int v = bt[j];
        int hrel = v >> 17;
        int t = v & 0x1FFFF;
        int pos = atomicAdd(&lcur[hrel], 1);
        tlist[pos] = t;
        hlist[pos] = lo + hrel;
    }
}

// ---- per-pass: dvinv = rsqrt(dvacc); egoS = bf16(ego * dvinv_t); zero dvacc ----
__global__ void k_scale(float* __restrict__ dvacc, float* __restrict__ dvinv,
                        const unsigned short* __restrict__ ego,
                        unsigned short* __restrict__ egoS) {
    int gid = blockIdx.x * blockDim.x + threadIdx.x;
    int wid = gid >> 6;
    int lane = threadIdx.x & 63;
    if (wid >= NTOT) return;
    int f = lane >> 4;
    float r = rsqrtf(fmaxf(dvacc[wid * 4 + f], 1e-8f));
    if ((lane & 15) == 0) dvinv[wid * 4 + f] = r;
    if (lane < 4) dvacc[wid * 4 + lane] = 0.f;   // wave-local: safe after read
    int i = wid * 64 + lane;
    egoS[i] = f2bf(bf2f(ego[i]) * r);
}

// ---- message passing: acc += w * egoS[t]; w = P or 0.25 (dvinv_t folded in egoS) ----
__global__ void k_mp(const unsigned short* __restrict__ egoS, const float* __restrict__ P,
                     const float* __restrict__ dvinv, const int* __restrict__ off,
                     const int* __restrict__ tlist,
                     unsigned short* __restrict__ fach, float* __restrict__ rhn,
                     unsigned short* __restrict__ tnhOut,
                     int useP, int writeRhn, int writeTnh) {
    int gid = blockIdx.x * blockDim.x + threadIdx.x;
    int wid = gid >> 6;
    int lane = threadIdx.x & 63;
    if (wid >= NTOT) return;
    int f = lane >> 4;
    int beg = off[wid], end = off[wid + 1];
    float dvh = dvinv[wid * 4 + f];
    float acc = 0.f;
    int j = beg;
    for (; j + 8 <= end; j += 8) {
        int t0 = tlist[j], t1 = tlist[j + 1], t2 = tlist[j + 2], t3 = tlist[j + 3];
        int t4 = tlist[j + 4], t5 = tlist[j + 5], t6 = tlist[j + 6], t7 = tlist[j + 7];
        float g0 = bf2f(egoS[(size_t)t0 * 64 + lane]), g1 = bf2f(egoS[(size_t)t1 * 64 + lane]),
              g2 = bf2f(egoS[(size_t)t2 * 64 + lane]), g3 = bf2f(egoS[(size_t)t3 * 64 + lane]),
              g4 = bf2f(egoS[(size_t)t4 * 64 + lane]), g5 = bf2f(egoS[(size_t)t5 * 64 + lane]),
              g6 = bf2f(egoS[(size_t)t6 * 64 + lane]), g7 = bf2f(egoS[(size_t)t7 * 64 + lane]);
        if (useP) {
            acc += P[(j + 0) * 4 + f] * g0 + P[(j + 1) * 4 + f] * g1
                 + P[(j + 2) * 4 + f] * g2 + P[(j + 3) * 4 + f] * g3
                 + P[(j + 4) * 4 + f] * g4 + P[(j + 5) * 4 + f] * g5
                 + P[(j + 6) * 4 + f] * g6 + P[(j + 7) * 4 + f] * g7;
        } else {
            acc += 0.25f * (g0 + g1 + g2 + g3 + g4 + g5 + g6 + g7);
        }
    }
    if (j + 4 <= end) {
        int t0 = tlist[j], t1 = tlist[j + 1], t2 = tlist[j + 2], t3 = tlist[j + 3];
        float g0 = bf2f(egoS[(size_t)t0 * 64 + lane]), g1 = bf2f(egoS[(size_t)t1 * 64 + lane]),
              g2 = bf2f(egoS[(size_t)t2 * 64 + lane]), g3 = bf2f(egoS[(size_t)t3 * 64 + lane]);
        if (useP) {
            acc += P[(j + 0) * 4 + f] * g0 + P[(j + 1) * 4 + f] * g1
                 + P[(j + 2) * 4 + f] * g2 + P[(j + 3) * 4 + f] * g3;
        } else {
            acc += 0.25f * (g0 + g1 + g2 + g3);
        }
        j += 4;
    }
    for (; j < end; ++j) {
        int t = tlist[j];
        float w = useP ? P[j * 4 + f] : 0.25f;
        acc += w * bf2f(egoS[(size_t)t * 64 + lane]);
    }
    acc *= dvh;
    fach[wid * 64 + lane] = f2bf(acc);
    if (writeRhn || writeTnh) {
        float ss = acc * acc;
        ss += __shfl_xor(ss, 1); ss += __shfl_xor(ss, 2);
        ss += __shfl_xor(ss, 4); ss += __shfl_xor(ss, 8);
        float rr = 1.0f / fmaxf(sqrtf(ss), 1e-12f);
        if (writeRhn && (lane & 15) == 0) rhn[wid * 4 + f] = rr;
        if (writeTnh) tnhOut[wid * 64 + lane] = f2bf(tanhf(acc * rr));
    }
}

// ---- routing update + fused dval via CSR-contiguous segmented reduction ----
__global__ void k_upd(const unsigned short* __restrict__ fach,
                      const unsigned short* __restrict__ tnhh,
                      const float* __restrict__ rhn,
                      const int* __restrict__ hlist, const int* __restrict__ tlist,
                      float* __restrict__ P, float* __restrict__ dval, int first) {
    __shared__ int   s_h[256];
    __shared__ float s_p[256][4];
    int tid = threadIdx.x;
    int j = blockIdx.x * 256 + tid;
    int h = -1;
    if (j < EDGES) {
        h = hlist[j];
        int t = tlist[j];
        const uint4* frow = (const uint4*)(fach + (size_t)h * 64);
        const uint4* trow = (const uint4*)(tnhh + (size_t)t * 64);
        float d[4];
#pragma unroll
        for (int f = 0; f < 4; ++f) {
            uint4 a0 = frow[f * 2], a1 = frow[f * 2 + 1];
            uint4 b0 = trow[f * 2], b1 = trow[f * 2 + 1];
            d[f] = dot2(a0.x, b0.x) + dot2(a0.y, b0.y)
                 + dot2(a0.z, b0.z) + dot2(a0.w, b0.w)
                 + dot2(a1.x, b1.x) + dot2(a1.y, b1.y)
                 + dot2(a1.z, b1.z) + dot2(a1.w, b1.w);
        }
        float4 rh = ((const float4*)rhn)[h];
        float lx, ly, lz, lw;
        if (first) { lx = ly = lz = lw = -LOG4; }
        else {
            float4 p0 = ((const float4*)P)[j];
            lx = __logf(p0.x); ly = __logf(p0.y);
            lz = __logf(p0.z); lw = __logf(p0.w);
        }
        float y0 = lx + rh.x * d[0], y1 = ly + rh.y * d[1],
              y2 = lz + rh.z * d[2], y3 = lw + rh.w * d[3];
        float m = fmaxf(fmaxf(y0, y1), fmaxf(y2, y3));
        float e0 = __expf(y0 - m), e1 = __expf(y1 - m),
              e2 = __expf(y2 - m), e3 = __expf(y3 - m);
        float inv = 1.0f / (e0 + e1 + e2 + e3);
        float p0n = e0 * inv, p1n = e1 * inv, p2n = e2 * inv, p3n = e3 * inv;
        ((float4*)P)[j] = make_float4(p0n, p1n, p2n, p3n);
        s_p[tid][0] = p0n; s_p[tid][1] = p1n; s_p[tid][2] = p2n; s_p[tid][3] = p3n;
    }
    s_h[tid] = h;
    __syncthreads();
    if (h == -1) return;
    if (tid > 0 && s_h[tid - 1] == h) return;   // not a segment head
    float a0 = 0.f, a1 = 0.f, a2 = 0.f, a3 = 0.f;
    int k = tid;
    while (k < 256 && s_h[k] == h) {
        a0 += s_p[k][0]; a1 += s_p[k][1]; a2 += s_p[k][2]; a3 += s_p[k][3];
        ++k;
    }
    float* dst = dval + (size_t)h * 4;
    if (tid == 0 || k == 256) {   // may continue in adjacent block -> atomic
        unsafeAtomicAdd(dst + 0, a0);
        unsafeAtomicAdd(dst + 1, a1);
        unsafeAtomicAdd(dst + 2, a2);
        unsafeAtomicAdd(dst + 3, a3);
    } else {                      // fully interior segment -> plain store
        ((float4*)dst)[0] = make_float4(a0, a1, a2, a3);
    }
}

// ---- final: out = (input + f1 + f3) / 3, single streaming pass ----
__global__ void k_final(const void* __restrict__ ue, const void* __restrict__ ie,
                        const int* __restrict__ flag,
                        const unsigned short* __restrict__ f1,
                        const unsigned short* __restrict__ f3,
                        float* __restrict__ out) {
    int i = blockIdx.x * blockDim.x + threadIdx.x;
    if (i >= NTOT * EMB) return;
    bool isf32 = (*flag != 0);
    float v;
    if (i < N_USER * EMB) {
        v = isf32 ? ((const float*)ue)[i]
                  : __bfloat162float(((const __hip_bfloat16*)ue)[i]);
    } else {
        int j = i - N_USER * EMB;
        v = isf32 ? ((const float*)ie)[j]
                  : __bfloat162float(((const __hip_bfloat16*)ie)[j]);
    }
    out[i] = (v + bf2f(f1[i]) + bf2f(f3[i])) * (1.0f / 3.0f);
}

extern "C" void kernel_launch(void* const* d_in, const int* in_sizes, int n_in,
                              void* d_out, int out_size, void* d_ws, size_t ws_size,
                              hipStream_t stream) {
    const void* ue = d_in[0];
    const void* ie = d_in[1];
    const int* hl = (const int*)d_in[2];
    const int* tl = (const int*)d_in[3];
    float* out = (float*)d_out;

    float* ws    = (float*)d_ws;
    float* P     = ws;
    int*   bt    = (int*)(ws);              // overlaps P (dead before P first written)
    int*   cnt   = (int*)(ws + 1000000);    // overlaps P
    int*   gbase = (int*)(ws + 1262144);    // overlaps P
    float* dvacc = ws + 4000000;
    float* dvinv = ws + 4320000;
    float* rhn   = ws + 4640000;
    unsigned short* bufW = (unsigned short*)(ws + 4960000);   // input ego; later f3
    unsigned short* bufX = (unsigned short*)(ws + 7520000);   // f0 / f2
    unsigned short* bufY = (unsigned short*)(ws + 10080000);  // f1 (layer-1 input)
    unsigned short* bufZ0 = (unsigned short*)(ws + 12640000); // layer-0 tnh
    unsigned short* bufZ1 = (unsigned short*)(ws + 15200000); // layer-1 tnh
    unsigned short* egoS = (unsigned short*)(ws + 17760000);  // ego * dvinv_t (per pass)
    int*   flag = (int*)(ws + 20320000);
    int*   deg  = (int*)(ws + 20320016);
    int*   off  = (int*)(ws + 20400016);
    int*   tlist = (int*)(ws + 20480017);
    int*   hlist = (int*)(ws + 21480017);
    int*   bsum  = (int*)(ws + 22480017);
    int*   bbase = (int*)(ws + 22480145);

    k_detect<<<1, 256, 0, stream>>>((const unsigned short*)ue, flag);
    k_init<<<20000, 256, 0, stream>>>(ue, ie, flag, bufW, bufZ0);

    hipMemsetAsync(deg, 0, NTOT * sizeof(int), stream);
    k_deg<<<3907, 256, 0, stream>>>(hl, deg);
    k_scan1<<<NBLK, SB, 0, stream>>>(deg, off, bsum);
    k_scan2<<<1, 128, 0, stream>>>(bsum, bbase);
    k_scan3<<<313, 256, 0, stream>>>(off, bbase, deg, dvacc);
    k_bcnt<<<BBLK, 256, 0, stream>>>(hl, cnt);
    k_bscan<<<NBUCK, BBLK, 0, stream>>>(cnt, off, gbase);
    k_bscat<<<BBLK, 256, 0, stream>>>(hl, tl, gbase, bt);
    k_bfin<<<NBUCK, 256, 0, stream>>>(bt, off, tlist, hlist);

    // layer 0
    k_scale<<<20000, 256, 0, stream>>>(dvacc, dvinv, bufW, egoS);  // pass-0 dv, zero dvacc
    k_mp<<<20000, 256, 0, stream>>>(egoS, P, dvinv, off, tlist, bufX, rhn, bufZ1,
                                    0, 1, 0);                      // p0 -> f0=X
    k_upd<<<3907, 256, 0, stream>>>(bufX, bufZ0, rhn, hlist, tlist, P, dvacc, 1);
    k_scale<<<20000, 256, 0, stream>>>(dvacc, dvinv, bufW, egoS);
    k_mp<<<20000, 256, 0, stream>>>(egoS, P, dvinv, off, tlist, bufY, rhn, bufZ1,
                                    1, 1, 1);                      // p1 -> f1=Y (+tnh1)
    k_upd<<<3907, 256, 0, stream>>>(bufY, bufZ0, rhn, hlist, tlist, P, dvacc, 0);
    // layer 1 (ego = Y)
    k_scale<<<20000, 256, 0, stream>>>(dvacc, dvinv, bufY, egoS);
    k_mp<<<20000, 256, 0, stream>>>(egoS, P, dvinv, off, tlist, bufX, rhn, bufZ1,
                                    1, 1, 0);                      // p2 -> f2=X
    k_upd<<<3907, 256, 0, stream>>>(bufX, bufZ1, rhn, hlist, tlist, P, dvacc, 0);
    k_scale<<<20000, 256, 0, stream>>>(dvacc, dvinv, bufY, egoS);
    k_mp<<<20000, 256, 0, stream>>>(egoS, P, dvinv, off, tlist, bufW, rhn, bufZ1,
                                    1, 0, 0);                      // p3 -> f3=W
    k_final<<<20000, 256, 0, stream>>>(ue, ie, flag, bufY, bufW, out);
}